// Round 11
// baseline (57.921 us; speedup 1.0000x reference)
//
#include <hip/hip_runtime.h>

// ConvAutoEncoder: B=16384, T=64, C=2, D=4
// out = [encoder_out (B*128 f32) | decoded (B*128 f32)]
// Fused kernel (R7 structure). Attention v2: only x pairs staged in LDS
// (32 b128 broadcast reads/batch instead of 64); u,v recomputed per lane via exp2
// (trans pipe). MFMA conv/decoder phases identical to R7.

typedef __attribute__((ext_vector_type(8))) short bf16x8;
typedef __attribute__((ext_vector_type(4))) float f32x4;

__device__ __forceinline__ unsigned short f2bf(float f) {
    unsigned int u = __builtin_bit_cast(unsigned int, f);
    return (unsigned short)((u + 0x7FFFu + ((u >> 16) & 1u)) >> 16);
}
__device__ __forceinline__ unsigned int pack2bf(float a, float b) {
    return (unsigned int)f2bf(a) | ((unsigned int)f2bf(b) << 16);
}

#define SWZ(row) (((row) & 7) << 3)   // ushort-index XOR == byte XOR ((row&7)<<4)

// ---------------- kernel 0: weight prep ----------------
__global__ void k0_prep(const float* __restrict__ w1, const float* __restrict__ w2,
                        const float* __restrict__ cw, const float* __restrict__ cb,
                        unsigned short* __restrict__ w1b, unsigned short* __restrict__ w2b,
                        unsigned short* __restrict__ wcv, float* __restrict__ biasf) {
    int i = blockIdx.x * 256 + threadIdx.x;      // 0..65535
    if (i < 512 * 128) { w1b[i] = f2bf(w1[i]); w2b[i] = f2bf(w2[i]); }
    if (i < 128 * 256) {
        int f = i >> 8, kd = i & 255;            // f = 2*o + s, kd = node*4 + d
        int o = f >> 1, s = f & 1, node = kd >> 2, d = kd & 3;
        int k = d - s;
        float v = (k >= 0 && k < 3) ? cw[o * 192 + node * 3 + k] : 0.f;
        wcv[i] = f2bf(v);
    }
    if (i < 128) biasf[i] = cb[i >> 1];
}

// ---------------- fused kernel ----------------
// 4 waves, 16 batches/block. Attention: wave wv rows 4wv..4wv+3 sequentially;
// per row, lane j = output node; neighbor x pairs broadcast from LDS, u,v recomputed.
// Conv: fb={wv,wv+4}. L1: nb=8wv..8wv+7. L2: mb={wv,wv+4}. Swizzled LDS between phases.
__global__ __launch_bounds__(256, 4) void k_fused(
    const float* __restrict__ x,             // (B,64,2)
    const float* __restrict__ W_gat,         // (4,2)
    const float* __restrict__ a_attn,        // (8,)
    const unsigned short* __restrict__ w1b,  // (512,128)
    const unsigned short* __restrict__ w2b,  // (128,512)
    const unsigned short* __restrict__ wcv,  // (128,256)
    const float* __restrict__ biasf,         // (128,)
    const float* __restrict__ b1,            // (512,)
    const float* __restrict__ b2,            // (128,)
    float* __restrict__ enc_out,             // (B,128) f32
    float* __restrict__ dec_out)             // (B,128) f32
{
    __shared__ __align__(16) unsigned char smem[28672];
    unsigned short* h_lds    = (unsigned short*)smem;            // [16][256] bf16 swz, 8KB
    unsigned short* flat_lds = (unsigned short*)(smem + 8192);   // [16][128] bf16 swz, 4KB
    float*          scr      = (float*)(smem + 12288);           // [4 waves][4 rows][128]f, 8KB } aliased
    unsigned short* hdec_lds = (unsigned short*)(smem + 12288);  // [16][512] bf16 swz, 16KB    }

    const int tid = threadIdx.x, lane = tid & 63, wv = tid >> 6;  // wv 0..3
    const int r = lane & 15, g = lane >> 4;
    const int base = blockIdx.x * 16;

    // ================= attention (4 rows per wave, x-only LDS broadcast) ==============
    {
        const float Wg00 = W_gat[0], Wg01 = W_gat[1], Wg10 = W_gat[2], Wg11 = W_gat[3];
        const float Wg20 = W_gat[4], Wg21 = W_gat[5], Wg30 = W_gat[6], Wg31 = W_gat[7];
        const float as0 = a_attn[0], as1 = a_attn[1], as2 = a_attn[2], as3 = a_attn[3];
        const float ad0 = a_attn[4], ad1 = a_attn[5], ad2 = a_attn[6], ad3 = a_attn[7];
        const float L2E = 1.4426950408889634f;
        const float SL = 0.2f;
        // esL = x0*cs0L + x1*cs1L   (log2-scaled fold of z@a_src)
        const float cs0L = (as0 * Wg00 + as1 * Wg10 + as2 * Wg20 + as3 * Wg30) * L2E;
        const float cs1L = (as0 * Wg01 + as1 * Wg11 + as2 * Wg21 + as3 * Wg31) * L2E;
        const float cd0L = (ad0 * Wg00 + ad1 * Wg10 + ad2 * Wg20 + ad3 * Wg30) * L2E;
        const float cd1L = (ad0 * Wg01 + ad1 * Wg11 + ad2 * Wg21 + ad3 * Wg31) * L2E;

        float* wbuf = scr + wv * 512;        // 4 rows x 64 float2 (x pairs)

        #pragma unroll
        for (int t = 0; t < 4; ++t) {
            const float2 xv = ((const float2*)x)[(size_t)(base + wv * 4 + t) * 64 + lane];
            ((float2*)(wbuf + t * 128))[lane] = xv;

            // per-output (lane-local) terms
            const float edL = xv.x * cd0L + xv.y * cd1L;
            const float U = __builtin_amdgcn_exp2f(edL);
            const float V = __builtin_amdgcn_exp2f(SL * edL);
            // self term (identical expression to in-loop -> exact cancellation)
            const float esLs = xv.x * cs0L + xv.y * cs1L;
            const float uS = __builtin_amdgcn_exp2f(esLs);
            const float vS = __builtin_amdgcn_exp2f(SL * esLs);
            const float pS = fmaxf(uS * U, vS * V);

            float Sa = 0.f, A0a = 0.f, A1a = 0.f;
            float Sb = 0.f, A0b = 0.f, A1b = 0.f;
            const float4* xb = (const float4*)(wbuf + t * 128);
            #pragma unroll 8
            for (int k = 0; k < 32; ++k) {
                const float4 p = xb[k];              // (x0a,x1a,x0b,x1b) broadcast
                const float esA = p.x * cs0L + p.y * cs1L;
                const float esB = p.z * cs0L + p.w * cs1L;
                const float uA = __builtin_amdgcn_exp2f(esA);
                const float vA = __builtin_amdgcn_exp2f(SL * esA);
                const float uB = __builtin_amdgcn_exp2f(esB);
                const float vB = __builtin_amdgcn_exp2f(SL * esB);
                const float PA = fmaxf(uA * U, vA * V);
                const float PB = fmaxf(uB * U, vB * V);
                Sa += PA;  A0a += PA * p.x;  A1a += PA * p.y;
                Sb += PB;  A0b += PB * p.z;  A1b += PB * p.w;
            }
            const float S  = (Sa + Sb) - pS;
            const float A0 = (A0a + A0b) - pS * xv.x;
            const float A1 = (A1a + A1b) - pS * xv.y;
            const float rs = 1.0f / S;
            const float h0 = (Wg00 * A0 + Wg01 * A1) * rs;
            const float h1 = (Wg10 * A0 + Wg11 * A1) * rs;
            const float h2 = (Wg20 * A0 + Wg21 * A1) * rs;
            const float h3 = (Wg30 * A0 + Wg31 * A1) * rs;
            const int lr = wv * 4 + t;
            const int hidx = (lr * 256 + lane * 4) ^ SWZ(lr);
            *(uint2*)(&h_lds[hidx]) = make_uint2(pack2bf(h0, h1), pack2bf(h2, h3));
        }
    }
    __syncthreads();

    // ================= conv (as matmul, K=256): fb = wv, wv+4 =================
    f32x4 accc[2];
    accc[0] = (f32x4){0.f, 0.f, 0.f, 0.f};
    accc[1] = (f32x4){0.f, 0.f, 0.f, 0.f};
    #pragma unroll
    for (int kc = 0; kc < 8; ++kc) {
        const bf16x8 hf  = *(const bf16x8*)(&h_lds[(r * 256 + kc * 32 + g * 8) ^ SWZ(r)]);
        const bf16x8 wfa = *(const bf16x8*)(wcv + (wv * 16 + r) * 256 + kc * 32 + g * 8);
        const bf16x8 wfb = *(const bf16x8*)(wcv + ((wv + 4) * 16 + r) * 256 + kc * 32 + g * 8);
        accc[0] = __builtin_amdgcn_mfma_f32_16x16x32_bf16(wfa, hf, accc[0], 0, 0, 0);
        accc[1] = __builtin_amdgcn_mfma_f32_16x16x32_bf16(wfb, hf, accc[1], 0, 0, 0);
    }
    #pragma unroll
    for (int q = 0; q < 2; ++q) {
        const int f0 = (wv + q * 4) * 16 + g * 4;
        const float4 bs = *(const float4*)(biasf + f0);
        const float v0 = accc[q][0] + bs.x, v1 = accc[q][1] + bs.y;
        const float v2 = accc[q][2] + bs.z, v3 = accc[q][3] + bs.w;
        *(float4*)(enc_out + (size_t)(base + r) * 128 + f0) = make_float4(v0, v1, v2, v3);
        const int fidx = (r * 128 + f0) ^ SWZ(r);
        *(uint2*)(&flat_lds[fidx]) = make_uint2(pack2bf(v0, v1), pack2bf(v2, v3));
    }
    __syncthreads();

    // ================= decoder layer1: 128 -> 512, relu; nb = 8wv..8wv+7 =================
    bf16x8 ff1[4];
    #pragma unroll
    for (int kb = 0; kb < 4; ++kb)
        ff1[kb] = *(const bf16x8*)(&flat_lds[(r * 128 + kb * 32 + g * 8) ^ SWZ(r)]);
    #pragma unroll
    for (int t = 0; t < 8; ++t) {
        const int nb = wv * 8 + t;
        f32x4 a1 = (f32x4){0.f, 0.f, 0.f, 0.f};
        #pragma unroll
        for (int kb = 0; kb < 4; ++kb) {
            const bf16x8 wf = *(const bf16x8*)(w1b + (nb * 16 + r) * 128 + kb * 32 + g * 8);
            a1 = __builtin_amdgcn_mfma_f32_16x16x32_bf16(wf, ff1[kb], a1, 0, 0, 0);
        }
        const int n0 = nb * 16 + g * 4;
        const float4 bs = *(const float4*)(b1 + n0);
        const float v0 = fmaxf(a1[0] + bs.x, 0.f);
        const float v1 = fmaxf(a1[1] + bs.y, 0.f);
        const float v2 = fmaxf(a1[2] + bs.z, 0.f);
        const float v3 = fmaxf(a1[3] + bs.w, 0.f);
        const int hdidx = (r * 512 + n0) ^ SWZ(r);
        *(uint2*)(&hdec_lds[hdidx]) = make_uint2(pack2bf(v0, v1), pack2bf(v2, v3));
    }
    __syncthreads();

    // ================= decoder layer2: 512 -> 128; mb = wv, wv+4 =================
    f32x4 acc2[2];
    acc2[0] = (f32x4){0.f, 0.f, 0.f, 0.f};
    acc2[1] = (f32x4){0.f, 0.f, 0.f, 0.f};
    #pragma unroll
    for (int np = 0; np < 16; ++np) {
        const bf16x8 hfd = *(const bf16x8*)(&hdec_lds[(r * 512 + np * 32 + g * 8) ^ SWZ(r)]);
        const bf16x8 wfa = *(const bf16x8*)(w2b + (wv * 16 + r) * 512 + np * 32 + g * 8);
        const bf16x8 wfb = *(const bf16x8*)(w2b + ((wv + 4) * 16 + r) * 512 + np * 32 + g * 8);
        acc2[0] = __builtin_amdgcn_mfma_f32_16x16x32_bf16(wfa, hfd, acc2[0], 0, 0, 0);
        acc2[1] = __builtin_amdgcn_mfma_f32_16x16x32_bf16(wfb, hfd, acc2[1], 0, 0, 0);
    }
    #pragma unroll
    for (int q = 0; q < 2; ++q) {
        const int m0 = (wv + q * 4) * 16 + g * 4;
        const float4 bs = *(const float4*)(b2 + m0);
        *(float4*)(dec_out + (size_t)(base + r) * 128 + m0) =
            make_float4(acc2[q][0] + bs.x, acc2[q][1] + bs.y,
                        acc2[q][2] + bs.z, acc2[q][3] + bs.w);
    }
}

extern "C" void kernel_launch(void* const* d_in, const int* in_sizes, int n_in,
                              void* d_out, int out_size, void* d_ws, size_t ws_size,
                              hipStream_t stream) {
    const float* x      = (const float*)d_in[0];
    const float* W_gat  = (const float*)d_in[1];
    const float* a_attn = (const float*)d_in[2];
    const float* conv_w = (const float*)d_in[3];
    const float* conv_b = (const float*)d_in[4];
    const float* dec_w1 = (const float*)d_in[5];
    const float* dec_b1 = (const float*)d_in[6];
    const float* dec_w2 = (const float*)d_in[7];
    const float* dec_b2 = (const float*)d_in[8];
    float* out = (float*)d_out;

    const int B = in_sizes[0] / 128;                 // 16384
    unsigned short* w1b = (unsigned short*)d_ws;     // 512*128
    unsigned short* w2b = w1b + 512 * 128;           // 128*512
    unsigned short* wcv = w2b + 128 * 512;           // 128*256
    float* biasf = (float*)(wcv + 128 * 256);        // 128

    k0_prep<<<256, 256, 0, stream>>>(dec_w1, dec_w2, conv_w, conv_b, w1b, w2b, wcv, biasf);

    k_fused<<<B / 16, 256, 0, stream>>>(x, W_gat, a_attn, w1b, w2b, wcv, biasf,
                                        dec_b1, dec_b2, out, out + (size_t)B * 128);
}